// Round 3
// baseline (226.368 us; speedup 1.0000x reference)
//
#include <hip/hip_runtime.h>
#include <hip/hip_bf16.h>

// Variable_Attention: out = softmax(relu((x@WQ)(x@WK)^T)/sqrt(128), axis=-1)
// B=16, N=2048, T=96, D=128. fp32 in/out.
//
// Restructure: QK^T = x M x^T with M = WQ WK^T (96x96).
//   k_split_x : x -> xh+xl (fp16 hi/lo split, error 2^-22 rel)
//   k_m       : M^T (transposed, fp32 exact) -> split mth/mtl
//   k_y       : y = x@M via split-fp16 MFMA (3-term), stored fp32
//   k_attn    : S = y@x^T (split-fp16 MFMA, K=96) fused relu/scale/softmax.
//               16 rows/block, 512 threads, NO LDS staging (waves read
//               disjoint cols -> no intra-block reuse; x is L2-resident per
//               XCD via bijective swizzle). ks-outer + ping-pong B prefetch
//               keeps regs ~115 -> 4 waves/SIMD, 2 blocks/CU so the 128KB
//               store drain overlaps the sibling block's MFMA.
// Workspace: ~25.3 MB.

typedef _Float16 f16;
typedef _Float16 half4 __attribute__((ext_vector_type(4)));
typedef _Float16 half8 __attribute__((ext_vector_type(8)));
typedef float float4v __attribute__((ext_vector_type(4)));

#define B_ 16
#define N_ 2048
#define T_ 96
#define D_ 128

// ---------------------------------------------------------------------------
// k_split_x: x (fp32) -> hi/lo fp16 pair.
// ---------------------------------------------------------------------------
__global__ void k_split_x(const float* __restrict__ x, f16* __restrict__ xh,
                          f16* __restrict__ xl, int n4) {
    int idx = blockIdx.x * 256 + threadIdx.x;
    if (idx >= n4) return;
    float4v v = ((const float4v*)x)[idx];
    half4 h, l;
#pragma unroll
    for (int j = 0; j < 4; ++j) {
        f16 hj = (f16)v[j];
        h[j] = hj;
        l[j] = (f16)(v[j] - (float)hj);
    }
    ((half4*)xh)[idx] = h;
    ((half4*)xl)[idx] = l;
}

// ---------------------------------------------------------------------------
// k_m: M[t][t2] = sum_d WQ[t,d]*WK[t2,d]  (fp32 exact), stored TRANSPOSED
// (mt*[t2][t]) and split to fp16 hi/lo so k_y's B-fragments are contiguous.
// ---------------------------------------------------------------------------
__global__ void k_m(const float* __restrict__ WQ, const float* __restrict__ WK,
                    f16* __restrict__ mth, f16* __restrict__ mtl) {
    int i = blockIdx.x * 256 + threadIdx.x;
    if (i >= T_ * T_) return;
    int t = i / T_, t2 = i % T_;
    const float4v* q = (const float4v*)(WQ + (size_t)t * D_);
    const float4v* k = (const float4v*)(WK + (size_t)t2 * D_);
    float s = 0.0f;
#pragma unroll
    for (int d = 0; d < D_ / 4; ++d) {
        float4v a = q[d], b = k[d];
        s += a[0] * b[0] + a[1] * b[1] + a[2] * b[2] + a[3] * b[3];
    }
    f16 h = (f16)s;
    mth[t2 * T_ + t] = h;
    mtl[t2 * T_ + t] = (f16)(s - (float)h);
}

// ---------------------------------------------------------------------------
// k_y: y = x @ M  (32768 x 96, K=96), split-fp16 MFMA 3-term, output fp32.
// 256 threads (4 waves), wave owns 32 rows; block = 128 rows.
// ---------------------------------------------------------------------------
__global__ __launch_bounds__(256) void k_y(
        const f16* __restrict__ xh, const f16* __restrict__ xl,
        const f16* __restrict__ mth, const f16* __restrict__ mtl,
        float* __restrict__ y) {
    const int lane = threadIdx.x & 63;
    const int wave = threadIdx.x >> 6;
    const int lr = lane & 15;
    const int lk = lane >> 4;
    const size_t mrow = (size_t)blockIdx.x * 128 + wave * 32;

    half8 aH[2][3], aL[2][3];
#pragma unroll
    for (int mt = 0; mt < 2; ++mt)
#pragma unroll
        for (int ks = 0; ks < 3; ++ks) {
            size_t off = (mrow + mt * 16 + lr) * T_ + ks * 32 + lk * 8;
            aH[mt][ks] = *(const half8*)(xh + off);
            aL[mt][ks] = *(const half8*)(xl + off);
        }

    float4v acc[2][6];
#pragma unroll
    for (int mt = 0; mt < 2; ++mt)
#pragma unroll
        for (int nt = 0; nt < 6; ++nt) {
            float4v z = {0.f, 0.f, 0.f, 0.f};
            acc[mt][nt] = z;
        }

#pragma unroll
    for (int nt = 0; nt < 6; ++nt) {
        half8 bH[3], bL[3];
#pragma unroll
        for (int ks = 0; ks < 3; ++ks) {
            size_t off = (size_t)(nt * 16 + lr) * T_ + ks * 32 + lk * 8;
            bH[ks] = *(const half8*)(mth + off);
            bL[ks] = *(const half8*)(mtl + off);
        }
#pragma unroll
        for (int ks = 0; ks < 3; ++ks)
#pragma unroll
            for (int mt = 0; mt < 2; ++mt) {
                acc[mt][nt] = __builtin_amdgcn_mfma_f32_16x16x32_f16(aH[mt][ks], bH[ks], acc[mt][nt], 0, 0, 0);
                acc[mt][nt] = __builtin_amdgcn_mfma_f32_16x16x32_f16(aH[mt][ks], bL[ks], acc[mt][nt], 0, 0, 0);
                acc[mt][nt] = __builtin_amdgcn_mfma_f32_16x16x32_f16(aL[mt][ks], bH[ks], acc[mt][nt], 0, 0, 0);
            }
    }

#pragma unroll
    for (int mt = 0; mt < 2; ++mt)
#pragma unroll
        for (int nt = 0; nt < 6; ++nt)
#pragma unroll
            for (int r = 0; r < 4; ++r)
                y[(mrow + mt * 16 + lk * 4 + r) * T_ + nt * 16 + lr] = acc[mt][nt][r];
}

// ---------------------------------------------------------------------------
// k_attn: S = y @ x^T fused with relu/scale/softmax.
// Block = 512 threads (8 waves) owns 16 rows x 2048 cols of one batch.
// Wave w owns cols [w*256, +256) = 16 col-tiles; acc[16] = 64 regs/lane.
// K=96 as 3 outer ksteps; per kstep the 16 col-tiles are visited with a
// ping-pong register prefetch of the B fragments (all indices static).
// No main-loop barriers; ~115 VGPR -> 4 waves/SIMD, 2 blocks/CU.
// ---------------------------------------------------------------------------
__global__ __launch_bounds__(512, 4) void k_attn(
        const f16* __restrict__ xh, const f16* __restrict__ xl,
        const float* __restrict__ y, float* __restrict__ out) {
    __shared__ float red[8][16];
    __shared__ float stat[16];

    const int tid  = (int)threadIdx.x;
    const int lane = tid & 63;
    const int wave = tid >> 6;
    const int lr = lane & 15;
    const int lk = lane >> 4;

    // XCD-aware bijective swizzle (2048 blocks % 8 == 0): per XCD a
    // contiguous logical range of 256 blocks = 2 batches' x (~1.5MB in L2).
    const int lb   = ((int)blockIdx.x & 7) * 256 + ((int)blockIdx.x >> 3);
    const int b    = lb >> 7;                 // batch
    const int row0 = (lb & 127) << 4;         // 16 rows per block
    const size_t xbase = (size_t)b * N_;
    const size_t obase = (size_t)b * N_ * N_;
    const int col0 = wave << 8;               // 256 cols per wave

    float4v acc[16];
#pragma unroll
    for (int c = 0; c < 16; ++c) {
        float4v z = {0.f, 0.f, 0.f, 0.f};
        acc[c] = z;
    }

#pragma unroll
    for (int ks = 0; ks < 3; ++ks) {
        // A fragment for this kstep: y row (fp32) split on the fly.
        const float* ap = y + (xbase + row0 + lr) * T_ + ks * 32 + lk * 8;
        float4v v0 = *(const float4v*)ap;
        float4v v1 = *(const float4v*)(ap + 4);
        half8 aH, aL;
#pragma unroll
        for (int j = 0; j < 4; ++j) {
            f16 h0 = (f16)v0[j]; aH[j] = h0; aL[j] = (f16)(v0[j] - (float)h0);
            f16 h1 = (f16)v1[j]; aH[4 + j] = h1; aL[4 + j] = (f16)(v1[j] - (float)h1);
        }

        const f16* bbase_h = xh + xbase * T_ + ks * 32 + lk * 8;
        const f16* bbase_l = xl + xbase * T_ + ks * 32 + lk * 8;

        half8 bh[2], bl[2];
        bh[0] = *(const half8*)(bbase_h + (size_t)(col0 + lr) * T_);
        bl[0] = *(const half8*)(bbase_l + (size_t)(col0 + lr) * T_);
#pragma unroll
        for (int c = 0; c < 16; ++c) {
            if (c < 15) {
                size_t boff = (size_t)(col0 + (c + 1) * 16 + lr) * T_;
                bh[(c + 1) & 1] = *(const half8*)(bbase_h + boff);
                bl[(c + 1) & 1] = *(const half8*)(bbase_l + boff);
            }
            acc[c] = __builtin_amdgcn_mfma_f32_16x16x32_f16(aH, bh[c & 1], acc[c], 0, 0, 0);
            acc[c] = __builtin_amdgcn_mfma_f32_16x16x32_f16(aH, bl[c & 1], acc[c], 0, 0, 0);
            acc[c] = __builtin_amdgcn_mfma_f32_16x16x32_f16(aL, bh[c & 1], acc[c], 0, 0, 0);
        }
    }

    // ---- relu + scale, row max (rows: lk*4+r, 0..15) ----
    const float scale = 0.088388347648318447f;  // 1/sqrt(128)
    float rmax[4];
#pragma unroll
    for (int r = 0; r < 4; ++r) rmax[r] = 0.0f;
#pragma unroll
    for (int c = 0; c < 16; ++c)
#pragma unroll
        for (int r = 0; r < 4; ++r) {
            float v = fmaxf(acc[c][r], 0.0f) * scale;
            acc[c][r] = v;
            rmax[r] = fmaxf(rmax[r], v);
        }
#pragma unroll
    for (int r = 0; r < 4; ++r) {
        float m = rmax[r];
        m = fmaxf(m, __shfl_xor(m, 1));
        m = fmaxf(m, __shfl_xor(m, 2));
        m = fmaxf(m, __shfl_xor(m, 4));
        m = fmaxf(m, __shfl_xor(m, 8));
        rmax[r] = m;
    }
    if (lr == 0) {
#pragma unroll
        for (int r = 0; r < 4; ++r)
            red[wave][lk * 4 + r] = rmax[r];
    }
    __syncthreads();
    if (tid < 16) {
        float m = red[0][tid];
#pragma unroll
        for (int w = 1; w < 8; ++w) m = fmaxf(m, red[w][tid]);
        stat[tid] = m;
    }
    __syncthreads();

    float rowm[4], rsum[4];
#pragma unroll
    for (int r = 0; r < 4; ++r) {
        rowm[r] = stat[lk * 4 + r];
        rsum[r] = 0.0f;
    }

    // ---- exp, row sum ----
#pragma unroll
    for (int c = 0; c < 16; ++c)
#pragma unroll
        for (int r = 0; r < 4; ++r) {
            float e = __expf(acc[c][r] - rowm[r]);
            acc[c][r] = e;
            rsum[r] += e;
        }
#pragma unroll
    for (int r = 0; r < 4; ++r) {
        float s = rsum[r];
        s += __shfl_xor(s, 1);
        s += __shfl_xor(s, 2);
        s += __shfl_xor(s, 4);
        s += __shfl_xor(s, 8);
        rsum[r] = s;
    }
    __syncthreads();   // red[] reuse
    if (lr == 0) {
#pragma unroll
        for (int r = 0; r < 4; ++r)
            red[wave][lk * 4 + r] = rsum[r];
    }
    __syncthreads();
    if (tid < 16) {
        float s = 0.0f;
#pragma unroll
        for (int w = 0; w < 8; ++w) s += red[w][tid];
        stat[tid] = s;
    }
    __syncthreads();

    float inv[4];
#pragma unroll
    for (int r = 0; r < 4; ++r)
        inv[r] = 1.0f / stat[lk * 4 + r];

    // ---- normalize + store ----
#pragma unroll
    for (int c = 0; c < 16; ++c)
#pragma unroll
        for (int r = 0; r < 4; ++r) {
            int grow = row0 + lk * 4 + r;
            int col = col0 + c * 16 + lr;
            out[obase + (size_t)grow * N_ + col] = acc[c][r] * inv[r];
        }
}

// ---------------------------------------------------------------------------
extern "C" void kernel_launch(void* const* d_in, const int* in_sizes, int n_in,
                              void* d_out, int out_size, void* d_ws, size_t ws_size,
                              hipStream_t stream) {
    const float* x  = (const float*)d_in[0];
    const float* WQ = (const float*)d_in[1];
    const float* WK = (const float*)d_in[2];
    float* out = (float*)d_out;

    char* ws = (char*)d_ws;
    size_t off = 0;
    auto carve = [&](size_t bytes) -> char* {
        char* p = ws + off;
        off += (bytes + 255) & ~(size_t)255;
        return p;
    };
    const size_t xelems = (size_t)B_ * N_ * T_;   // 3145728
    f16*   xh  = (f16*)carve(xelems * 2);
    f16*   xl  = (f16*)carve(xelems * 2);
    f16*   mth = (f16*)carve((size_t)T_ * T_ * 2);
    f16*   mtl = (f16*)carve((size_t)T_ * T_ * 2);
    float* yw  = (float*)carve((size_t)B_ * N_ * T_ * 4);
    (void)ws_size; (void)in_sizes; (void)n_in; (void)out_size;

    int n4 = (int)(xelems / 4);
    k_split_x<<<(n4 + 255) / 256, 256, 0, stream>>>(x, xh, xl, n4);
    k_m<<<(T_ * T_ + 255) / 256, 256, 0, stream>>>(WQ, WK, mth, mtl);
    k_y<<<(B_ * N_) / 128, 256, 0, stream>>>(xh, xl, mth, mtl, yw);
    k_attn<<<B_ * (N_ / 16), 512, 0, stream>>>(xh, xl, yw, out);
}

// Round 4
// 158.114 us; speedup vs baseline: 1.4317x; 1.4317x over previous
//
#include <hip/hip_runtime.h>
#include <hip/hip_bf16.h>

// Variable_Attention: out = softmax(relu((x@WQ)(x@WK)^T)/sqrt(128), axis=-1)
// B=16, N=2048, T=96, D=128. fp32 in/out.
//
// QK^T = x M x^T with M = WQ WK^T (96x96):
//   k_m    : M^T exact fp32 -> fp16 hi/lo split (mth/mtl)
//   k_y    : y = x@M, split-fp16 MFMA 3-term (A split on the fly from fp32 x)
//   k_pack : x -> Bp, fp16 hi/lo split packed in MFMA B-fragment stream order
//            Bp[b][ct(128)][ks(3)][hl(2)][lane(64)][8] - a wave's fragment
//            load = contiguous 1KB; Bp/batch = 786KB (L2-resident per XCD)
//   k_attn : S = y@x^T (K=96, 3-term split-fp16) fused relu/scale/softmax.
//            BM=32 rows/block, 512 thr, wave owns 256 cols; acc[2][16]=128.
//            Depth-2 register ping-pong B prefetch, no LDS/barriers in loop,
//            nontemporal out stores (protect L2 residency of Bp).
// Workspace: ~25.3 MB.

typedef _Float16 f16;
typedef _Float16 half8 __attribute__((ext_vector_type(8)));
typedef float float4v __attribute__((ext_vector_type(4)));

#define B_ 16
#define N_ 2048
#define T_ 96
#define D_ 128

// ---------------------------------------------------------------------------
// k_m: M[t][t2] = sum_d WQ[t,d]*WK[t2,d] (fp32 exact), stored transposed and
// split to fp16 hi/lo.
// ---------------------------------------------------------------------------
__global__ void k_m(const float* __restrict__ WQ, const float* __restrict__ WK,
                    f16* __restrict__ mth, f16* __restrict__ mtl) {
    int i = blockIdx.x * 256 + threadIdx.x;
    if (i >= T_ * T_) return;
    int t = i / T_, t2 = i % T_;
    const float4v* q = (const float4v*)(WQ + (size_t)t * D_);
    const float4v* k = (const float4v*)(WK + (size_t)t2 * D_);
    float s = 0.0f;
#pragma unroll
    for (int d = 0; d < D_ / 4; ++d) {
        float4v a = q[d], b = k[d];
        s += a[0] * b[0] + a[1] * b[1] + a[2] * b[2] + a[3] * b[3];
    }
    f16 h = (f16)s;
    mth[t2 * T_ + t] = h;
    mtl[t2 * T_ + t] = (f16)(s - (float)h);
}

// ---------------------------------------------------------------------------
// k_pack: x (fp32) -> Bp fragment-stream layout, fp16 hi/lo.
// Bp index: ((((b*128+ct)*3+ks)*2+hl)*64+lane)*8 + j
// value   : split of x[b][ct*16+(lane&15)][ks*32+(lane>>4)*8+j]
// One thread per (b,ct,ks,lane): reads 32B of x, writes hi+lo half8.
// ---------------------------------------------------------------------------
__global__ void k_pack(const float* __restrict__ x, f16* __restrict__ bp) {
    int idx = blockIdx.x * 256 + threadIdx.x;   // (b*128+ct)*3*64 + ks*64 + lane
    if (idx >= B_ * 128 * 3 * 64) return;
    int lane = idx & 63;
    int ks   = (idx >> 6) % 3;
    int ct   = (idx / (64 * 3)) & 127;
    int b    = idx / (64 * 3 * 128);
    int col  = ct * 16 + (lane & 15);
    int k0   = ks * 32 + (lane >> 4) * 8;
    const float* src = x + ((size_t)b * N_ + col) * T_ + k0;
    float4v v0 = *(const float4v*)src;
    float4v v1 = *(const float4v*)(src + 4);
    half8 h, l;
#pragma unroll
    for (int j = 0; j < 4; ++j) {
        f16 h0 = (f16)v0[j]; h[j] = h0; l[j] = (f16)(v0[j] - (float)h0);
        f16 h1 = (f16)v1[j]; h[4 + j] = h1; l[4 + j] = (f16)(v1[j] - (float)h1);
    }
    size_t obase = ((((size_t)b * 128 + ct) * 3 + ks) * 2) * 64 * 8 + (size_t)lane * 8;
    *(half8*)(bp + obase) = h;
    *(half8*)(bp + obase + 512) = l;
}

// ---------------------------------------------------------------------------
// k_y: y = x @ M (32768 x 96, K=96), split-fp16 MFMA 3-term, fp32 out.
// 256 threads (4 waves), wave owns 32 rows; A split on the fly from fp32 x.
// ---------------------------------------------------------------------------
__global__ __launch_bounds__(256) void k_y(
        const float* __restrict__ x,
        const f16* __restrict__ mth, const f16* __restrict__ mtl,
        float* __restrict__ y) {
    const int lane = threadIdx.x & 63;
    const int wave = threadIdx.x >> 6;
    const int lr = lane & 15;
    const int lk = lane >> 4;
    const size_t mrow = (size_t)blockIdx.x * 128 + wave * 32;

    half8 aH[2][3], aL[2][3];
#pragma unroll
    for (int mt = 0; mt < 2; ++mt)
#pragma unroll
        for (int ks = 0; ks < 3; ++ks) {
            const float* p = x + (mrow + mt * 16 + lr) * T_ + ks * 32 + lk * 8;
            float4v v0 = *(const float4v*)p;
            float4v v1 = *(const float4v*)(p + 4);
            half8 h, l;
#pragma unroll
            for (int j = 0; j < 4; ++j) {
                f16 h0 = (f16)v0[j]; h[j] = h0; l[j] = (f16)(v0[j] - (float)h0);
                f16 h1 = (f16)v1[j]; h[4 + j] = h1; l[4 + j] = (f16)(v1[j] - (float)h1);
            }
            aH[mt][ks] = h;
            aL[mt][ks] = l;
        }

    float4v acc[2][6];
#pragma unroll
    for (int mt = 0; mt < 2; ++mt)
#pragma unroll
        for (int nt = 0; nt < 6; ++nt) {
            float4v z = {0.f, 0.f, 0.f, 0.f};
            acc[mt][nt] = z;
        }

#pragma unroll
    for (int nt = 0; nt < 6; ++nt) {
        half8 bH[3], bL[3];
#pragma unroll
        for (int ks = 0; ks < 3; ++ks) {
            size_t off = (size_t)(nt * 16 + lr) * T_ + ks * 32 + lk * 8;
            bH[ks] = *(const half8*)(mth + off);
            bL[ks] = *(const half8*)(mtl + off);
        }
#pragma unroll
        for (int ks = 0; ks < 3; ++ks)
#pragma unroll
            for (int mt = 0; mt < 2; ++mt) {
                acc[mt][nt] = __builtin_amdgcn_mfma_f32_16x16x32_f16(aH[mt][ks], bH[ks], acc[mt][nt], 0, 0, 0);
                acc[mt][nt] = __builtin_amdgcn_mfma_f32_16x16x32_f16(aH[mt][ks], bL[ks], acc[mt][nt], 0, 0, 0);
                acc[mt][nt] = __builtin_amdgcn_mfma_f32_16x16x32_f16(aL[mt][ks], bH[ks], acc[mt][nt], 0, 0, 0);
            }
    }

#pragma unroll
    for (int mt = 0; mt < 2; ++mt)
#pragma unroll
        for (int nt = 0; nt < 6; ++nt)
#pragma unroll
            for (int r = 0; r < 4; ++r)
                y[(mrow + mt * 16 + lk * 4 + r) * T_ + nt * 16 + lr] = acc[mt][nt][r];
}

// ---------------------------------------------------------------------------
// k_attn: S = y @ x^T fused relu/scale/softmax. 32 rows x 2048 cols per block.
// ---------------------------------------------------------------------------
__global__ __launch_bounds__(512, 2) void k_attn(
        const f16* __restrict__ bp, const float* __restrict__ y,
        float* __restrict__ out) {
    __shared__ float red[8][32];
    __shared__ float stat[32];

    const int tid  = (int)threadIdx.x;
    const int lane = tid & 63;
    const int wave = tid >> 6;
    const int lr = lane & 15;
    const int lk = lane >> 4;

    // XCD-aware bijective swizzle (1024 blocks, 8 XCDs): contiguous logical
    // range per XCD -> ~1-2 batches' Bp (0.8-1.6MB) L2-resident.
    const int lb   = ((int)blockIdx.x & 7) * 128 + ((int)blockIdx.x >> 3);
    const int b    = lb >> 6;
    const int row0 = (lb & 63) << 5;          // 32 rows per block
    const size_t obase = (size_t)b * N_ * N_;

    // ---- A: y rows (fp32) split on the fly ----
    half8 aH[2][3], aL[2][3];
#pragma unroll
    for (int mt = 0; mt < 2; ++mt)
#pragma unroll
        for (int ks = 0; ks < 3; ++ks) {
            const float* p = y + ((size_t)b * N_ + row0 + mt * 16 + lr) * T_ + ks * 32 + lk * 8;
            float4v v0 = *(const float4v*)p;
            float4v v1 = *(const float4v*)(p + 4);
            half8 h, l;
#pragma unroll
            for (int j = 0; j < 4; ++j) {
                f16 h0 = (f16)v0[j]; h[j] = h0; l[j] = (f16)(v0[j] - (float)h0);
                f16 h1 = (f16)v1[j]; h[4 + j] = h1; l[4 + j] = (f16)(v1[j] - (float)h1);
            }
            aH[mt][ks] = h;
            aL[mt][ks] = l;
        }

    float4v acc[2][16];
#pragma unroll
    for (int mt = 0; mt < 2; ++mt)
#pragma unroll
        for (int c = 0; c < 16; ++c) {
            float4v z = {0.f, 0.f, 0.f, 0.f};
            acc[mt][c] = z;
        }

    // ---- main loop: B streamed from Bp, depth-2 register ping-pong ----
    // wave's col-tiles: ct = wave*16 + c, c = 0..15. Per ct: 6 contiguous
    // 1KB fragments (ks x hl). Fragment addr (f16): base + c*3072 + f*512.
    const f16* wbase = bp + (((size_t)b * 128 + wave * 16) * 6) * 512 + (size_t)lane * 8;

    half8 Bf[2][6];
#pragma unroll
    for (int f = 0; f < 6; ++f) {
        Bf[0][f] = *(const half8*)(wbase + f * 512);
        Bf[1][f] = *(const half8*)(wbase + 3072 + f * 512);
    }

#pragma unroll
    for (int c = 0; c < 16; ++c) {
        const int cur = c & 1;
#pragma unroll
        for (int ks = 0; ks < 3; ++ks)
#pragma unroll
            for (int mt = 0; mt < 2; ++mt) {
                acc[mt][c] = __builtin_amdgcn_mfma_f32_16x16x32_f16(aH[mt][ks], Bf[cur][ks * 2], acc[mt][c], 0, 0, 0);
                acc[mt][c] = __builtin_amdgcn_mfma_f32_16x16x32_f16(aH[mt][ks], Bf[cur][ks * 2 + 1], acc[mt][c], 0, 0, 0);
                acc[mt][c] = __builtin_amdgcn_mfma_f32_16x16x32_f16(aL[mt][ks], Bf[cur][ks * 2], acc[mt][c], 0, 0, 0);
            }
        if (c + 2 < 16) {
            const f16* nb = wbase + (size_t)(c + 2) * 3072;
#pragma unroll
            for (int f = 0; f < 6; ++f)
                Bf[cur][f] = *(const half8*)(nb + f * 512);
        }
    }

    // ---- relu + scale, row max ----
    const float scale = 0.088388347648318447f;  // 1/sqrt(128)
    float rmax[2][4];
#pragma unroll
    for (int mt = 0; mt < 2; ++mt)
#pragma unroll
        for (int r = 0; r < 4; ++r) rmax[mt][r] = 0.0f;
#pragma unroll
    for (int mt = 0; mt < 2; ++mt)
#pragma unroll
        for (int c = 0; c < 16; ++c)
#pragma unroll
            for (int r = 0; r < 4; ++r) {
                float v = fmaxf(acc[mt][c][r], 0.0f) * scale;
                acc[mt][c][r] = v;
                rmax[mt][r] = fmaxf(rmax[mt][r], v);
            }
#pragma unroll
    for (int mt = 0; mt < 2; ++mt)
#pragma unroll
        for (int r = 0; r < 4; ++r) {
            float m = rmax[mt][r];
            m = fmaxf(m, __shfl_xor(m, 1));
            m = fmaxf(m, __shfl_xor(m, 2));
            m = fmaxf(m, __shfl_xor(m, 4));
            m = fmaxf(m, __shfl_xor(m, 8));
            rmax[mt][r] = m;
        }
    if (lr == 0) {
#pragma unroll
        for (int mt = 0; mt < 2; ++mt)
#pragma unroll
            for (int r = 0; r < 4; ++r)
                red[wave][mt * 16 + lk * 4 + r] = rmax[mt][r];
    }
    __syncthreads();
    if (tid < 32) {
        float m = red[0][tid];
#pragma unroll
        for (int w = 1; w < 8; ++w) m = fmaxf(m, red[w][tid]);
        stat[tid] = m;
    }
    __syncthreads();

    float rowm[2][4], rsum[2][4];
#pragma unroll
    for (int mt = 0; mt < 2; ++mt)
#pragma unroll
        for (int r = 0; r < 4; ++r) {
            rowm[mt][r] = stat[mt * 16 + lk * 4 + r];
            rsum[mt][r] = 0.0f;
        }

    // ---- exp, row sum ----
#pragma unroll
    for (int mt = 0; mt < 2; ++mt)
#pragma unroll
        for (int c = 0; c < 16; ++c)
#pragma unroll
            for (int r = 0; r < 4; ++r) {
                float e = __expf(acc[mt][c][r] - rowm[mt][r]);
                acc[mt][c][r] = e;
                rsum[mt][r] += e;
            }
#pragma unroll
    for (int mt = 0; mt < 2; ++mt)
#pragma unroll
        for (int r = 0; r < 4; ++r) {
            float s = rsum[mt][r];
            s += __shfl_xor(s, 1);
            s += __shfl_xor(s, 2);
            s += __shfl_xor(s, 4);
            s += __shfl_xor(s, 8);
            rsum[mt][r] = s;
        }
    __syncthreads();
    if (lr == 0) {
#pragma unroll
        for (int mt = 0; mt < 2; ++mt)
#pragma unroll
            for (int r = 0; r < 4; ++r)
                red[wave][mt * 16 + lk * 4 + r] = rsum[mt][r];
    }
    __syncthreads();
    if (tid < 32) {
        float s = 0.0f;
#pragma unroll
        for (int w = 0; w < 8; ++w) s += red[w][tid];
        stat[tid] = s;
    }
    __syncthreads();

    float inv[2][4];
#pragma unroll
    for (int mt = 0; mt < 2; ++mt)
#pragma unroll
        for (int r = 0; r < 4; ++r)
            inv[mt][r] = 1.0f / stat[mt * 16 + lk * 4 + r];

    // ---- normalize + nontemporal store ----
#pragma unroll
    for (int mt = 0; mt < 2; ++mt)
#pragma unroll
        for (int c = 0; c < 16; ++c)
#pragma unroll
            for (int r = 0; r < 4; ++r) {
                int grow = row0 + mt * 16 + lk * 4 + r;
                int col = (wave << 8) + c * 16 + lr;
                __builtin_nontemporal_store(acc[mt][c][r] * inv[mt][r],
                                            &out[obase + (size_t)grow * N_ + col]);
            }
}

// ---------------------------------------------------------------------------
extern "C" void kernel_launch(void* const* d_in, const int* in_sizes, int n_in,
                              void* d_out, int out_size, void* d_ws, size_t ws_size,
                              hipStream_t stream) {
    const float* x  = (const float*)d_in[0];
    const float* WQ = (const float*)d_in[1];
    const float* WK = (const float*)d_in[2];
    float* out = (float*)d_out;

    char* ws = (char*)d_ws;
    size_t off = 0;
    auto carve = [&](size_t bytes) -> char* {
        char* p = ws + off;
        off += (bytes + 255) & ~(size_t)255;
        return p;
    };
    f16*   mth = (f16*)carve((size_t)T_ * T_ * 2);
    f16*   mtl = (f16*)carve((size_t)T_ * T_ * 2);
    f16*   bpk = (f16*)carve((size_t)B_ * N_ * T_ * 2 * 2);   // 25.2 MB
    float* yw  = (float*)carve((size_t)B_ * N_ * T_ * 4);     // 12.6 MB
    (void)ws_size; (void)in_sizes; (void)n_in; (void)out_size;

    k_m<<<(T_ * T_ + 255) / 256, 256, 0, stream>>>(WQ, WK, mth, mtl);
    k_pack<<<(B_ * 128 * 3 * 64) / 256, 256, 0, stream>>>(x, bpk);
    k_y<<<(B_ * N_) / 128, 256, 0, stream>>>(x, mth, mtl, yw);
    k_attn<<<B_ * (N_ / 32), 512, 0, stream>>>(bpk, yw, out);
}